// Round 6
// baseline (227.644 us; speedup 1.0000x reference)
//
#include <hip/hip_runtime.h>
#include <stdint.h>
#include <stddef.h>

#define NN 4096
#define KK 1024
#define SPAN 4095u

typedef unsigned short ushort_t;
typedef __attribute__((ext_vector_type(8))) short short8v;   // 8 bf16 = 4 VGPR
typedef __attribute__((ext_vector_type(4))) float f32x4;     // MFMA C/D

// ---------------- Threefry-2x32, 20 rounds (exact JAX algorithm) -------------
__host__ __device__ inline void tf2x32(uint32_t k0, uint32_t k1,
                                       uint32_t x0, uint32_t x1,
                                       uint32_t* o0, uint32_t* o1) {
  uint32_t ks2 = k0 ^ k1 ^ 0x1BD11BDAu;
  uint32_t v0 = x0 + k0;
  uint32_t v1 = x1 + k1;
#define TF_ROT(x, r) (((x) << (r)) | ((x) >> (32 - (r))))
#define TF_RND(r) do { v0 += v1; v1 = TF_ROT(v1, r); v1 ^= v0; } while (0)
  TF_RND(13); TF_RND(15); TF_RND(26); TF_RND(6);
  v0 += k1;  v1 += ks2 + 1u;
  TF_RND(17); TF_RND(29); TF_RND(16); TF_RND(24);
  v0 += ks2; v1 += k0 + 2u;
  TF_RND(13); TF_RND(15); TF_RND(26); TF_RND(6);
  v0 += k0;  v1 += k1 + 3u;
  TF_RND(17); TF_RND(29); TF_RND(16); TF_RND(24);
  v0 += k1;  v1 += ks2 + 4u;
  TF_RND(13); TF_RND(15); TF_RND(26); TF_RND(6);
  v0 += ks2; v1 += k0 + 5u;
#undef TF_RND
#undef TF_ROT
  *o0 = v0; *o1 = v1;
}

__device__ inline uint32_t rb32(uint32_t ka, uint32_t kb, uint32_t i) {
  uint32_t a, b;
  tf2x32(ka, kb, 0u, i, &a, &b);
  return a ^ b;
}

// Monotone order-preserving float<->uint32 encoding; 0 == "no candidate".
__device__ inline uint32_t fenc(float f) {
  uint32_t b = __float_as_uint(f);
  return (b & 0x80000000u) ? ~b : (b | 0x80000000u);
}
__device__ inline float fdec(uint32_t e) {
  uint32_t b = (e & 0x80000000u) ? (e & 0x7FFFFFFFu) : ~e;
  return __uint_as_float(b);
}

__device__ inline ushort_t bf16rne(float f) {   // fp32 -> bf16 round-nearest-even
  uint32_t u = __float_as_uint(f);
  return (ushort_t)((u + 0x7FFFu + ((u >> 16) & 1u)) >> 16);
}

__device__ inline void glds16(const void* g, void* l) {
  __builtin_amdgcn_global_load_lds((const __attribute__((address_space(1))) void*)g,
                                   (__attribute__((address_space(3))) void*)l, 16, 0, 0);
}

// ---------------- Kernel 1: fp32->bf16 convert for X,Y + zero max tables -----
__global__ __launch_bounds__(256) void k_prep(
    const float4* __restrict__ X, const float4* __restrict__ Y,
    ushort4* __restrict__ Xb, ushort4* __restrict__ Yb,
    uint32_t* __restrict__ rowmax, uint32_t* __restrict__ colmax) {
  const int b = blockIdx.x, tid = threadIdx.x;
  if (b < 16) rowmax[b * 256 + tid] = 0u;
  else if (b < 32) colmax[(b - 16) * 256 + tid] = 0u;
  const float4* src = (b < 2048) ? X : Y;
  ushort4* dst = (b < 2048) ? Xb : Yb;
  const int n4 = NN * KK / 4;
  for (int i = (b & 2047) * 256 + tid; i < n4; i += 2048 * 256) {
    float4 v = src[i];
    ushort4 o;
    o.x = bf16rne(v.x); o.y = bf16rne(v.y); o.z = bf16rne(v.z); o.w = bf16rne(v.w);
    dst[i] = o;
  }
}

// ---------------- Kernel 2: anchors + 4 gathered imposter dots (inline PRNG) -
__global__ __launch_bounds__(256) void k_dots(
    const float* __restrict__ X, const float* __restrict__ Y,
    uint32_t s0a, uint32_t s0b, uint32_t s1a, uint32_t s1b,
    uint32_t s2a, uint32_t s2b, uint32_t s3a, uint32_t s3b,
    float* __restrict__ anchor, float* __restrict__ irr, float* __restrict__ irf,
    float* __restrict__ icr, float* __restrict__ icf) {
  const int wid = threadIdx.x >> 6;
  const int lane = threadIdx.x & 63;
  const int row = blockIdx.x * 4 + wid;

  int jl = 0;
  if (lane < 4) {
    uint32_t ka = (lane == 0) ? s0a : (lane == 1) ? s1a : (lane == 2) ? s2a : s3a;
    uint32_t kb = (lane == 0) ? s0b : (lane == 1) ? s1b : (lane == 2) ? s2b : s3b;
    uint32_t k1a, k1b, k2a, k2b;
    tf2x32(ka, kb, 0u, 0u, &k1a, &k1b);
    tf2x32(ka, kb, 0u, 1u, &k2a, &k2b);
    uint32_t hi = rb32(k1a, k1b, (uint32_t)row);
    uint32_t lo = rb32(k2a, k2b, (uint32_t)row);
    uint32_t off = ((hi % SPAN) * 256u + (lo % SPAN)) % SPAN;
    int j = (int)off;
    jl = j + ((j >= row) ? 1 : 0);
  }
  const int j1r = __shfl(jl, 0), j1f = __shfl(jl, 1);
  const int j2r = __shfl(jl, 2), j2f = __shfl(jl, 3);

  const float4* xk = (const float4*)(X + (size_t)row * KK);
  const float4* yk = (const float4*)(Y + (size_t)row * KK);
  const float4* y1 = (const float4*)(Y + (size_t)j1r * KK);
  const float4* y2 = (const float4*)(Y + (size_t)j1f * KK);
  const float4* x1 = (const float4*)(X + (size_t)j2r * KK);
  const float4* x2 = (const float4*)(X + (size_t)j2f * KK);
  float sa = 0.f, s1 = 0.f, s2 = 0.f, s3 = 0.f, s4 = 0.f;
  for (int t = lane; t < KK / 4; t += 64) {
    float4 xv = xk[t], yv = yk[t], a1 = y1[t], a2 = y2[t], b1 = x1[t], b2 = x2[t];
    sa = fmaf(xv.x, yv.x, fmaf(xv.y, yv.y, fmaf(xv.z, yv.z, fmaf(xv.w, yv.w, sa))));
    s1 = fmaf(xv.x, a1.x, fmaf(xv.y, a1.y, fmaf(xv.z, a1.z, fmaf(xv.w, a1.w, s1))));
    s2 = fmaf(xv.x, a2.x, fmaf(xv.y, a2.y, fmaf(xv.z, a2.z, fmaf(xv.w, a2.w, s2))));
    s3 = fmaf(b1.x, yv.x, fmaf(b1.y, yv.y, fmaf(b1.z, yv.z, fmaf(b1.w, yv.w, s3))));
    s4 = fmaf(b2.x, yv.x, fmaf(b2.y, yv.y, fmaf(b2.z, yv.z, fmaf(b2.w, yv.w, s4))));
  }
  for (int m = 32; m >= 1; m >>= 1) {
    sa += __shfl_xor(sa, m);
    s1 += __shfl_xor(s1, m);
    s2 += __shfl_xor(s2, m);
    s3 += __shfl_xor(s3, m);
    s4 += __shfl_xor(s4, m);
  }
  if (lane == 0) {
    anchor[row] = sa; irr[row] = s1; irf[row] = s2; icr[row] = s3; icf[row] = s4;
  }
}

// ------ Kernel 3: 256x256 MFMA GEMM, wave-pipelined + ABLATION variants ------
// V=0 full (real output). V=1 no-glds (ds_read+MFMA+sync cost). V=2 no-ds_read
// (glds+MFMA+sync cost). V=3 MFMA-only. V1-V3 write scratch tables.
// Schedule (V0), per K-tile t (buf d=t&1), ONE barrier per tile:
//   issue R2=A47+B23(12 reads,d); lgkm(12)[R1 done]; Q1(A03xB01);
//   lgkm(0)[R2 done]; Q2(A03xB23); vmcnt(0)[S(t+1) done, issued 1 tile ago];
//   issue A03(t+1); Q3(A47xB01); issue B01(t+1); [fence+barrier: all waves'
//   tile-t reads complete]; stage S(t+2)->d (8 glds, WAR-safe); Q4(A47xB23).
// ds_reads for t+1 fly under Q3/Q4 + next tile's Q1 (counted lgkm, no drain);
// glds issue->consume distance ~2 K-tiles >> 900cy HBM latency.

template<int V>
__global__ __launch_bounds__(512, 2) void k_gemm_pl(
    const ushort_t* __restrict__ A, const ushort_t* __restrict__ B,
    const float* __restrict__ anchor,
    uint32_t* __restrict__ rowmax, uint32_t* __restrict__ colmax) {
  __shared__ ushort_t AL[2][2][8192];   // [dbuf][half][128 rows x 64 k]
  __shared__ ushort_t BL[2][2][8192];

  constexpr bool DO_G = (V == 0 || V == 2);   // global_load_lds staging
  constexpr bool DO_D = (V == 0 || V == 1);   // per-tile ds_reads
  constexpr bool DO_S = (V != 3);             // barriers + waitcnt pacing

  const int tid = threadIdx.x;
  const int lane = tid & 63;
  const int w = tid >> 6, wr = w >> 2, wc = w & 3;   // 8 waves: 2M x 4N
  const int l15 = lane & 15, l4 = lane >> 4;

  const int swz = (blockIdx.x & 7) * 32 + (blockIdx.x >> 3);
  const int bi = swz >> 4, bj = swz & 15;

  const int strow = tid >> 3;
  const int scol = ((tid & 7) ^ (strow & 7)) * 8;
  const ushort_t* Abase = A + (size_t)(bi * 256 + strow) * KK + scol;
  const ushort_t* Bbase = B + (size_t)(bj * 256 + strow) * KK + scol;

  const int ss0 = ((0 * 4 + l4) ^ (l15 & 7)) * 8;
  const int ss1 = ((1 * 4 + l4) ^ (l15 & 7)) * 8;
  const int bhalf = wc >> 1, brow0 = (wc & 1) * 64 + l15;

  f32x4 acc[8][4] = {};
  short8v a03[4][2], a47[4][2], b01[2][2], b23[2][2];

#define STAGE(DD, KT)                                                          \
  do {                                                                         \
    glds16(Abase + (size_t)0 * KK + (KT) * 64,   &AL[DD][0][tid * 8]);         \
    glds16(Abase + (size_t)64 * KK + (KT) * 64,  &AL[DD][0][4096 + tid * 8]);  \
    glds16(Abase + (size_t)128 * KK + (KT) * 64, &AL[DD][1][tid * 8]);         \
    glds16(Abase + (size_t)192 * KK + (KT) * 64, &AL[DD][1][4096 + tid * 8]);  \
    glds16(Bbase + (size_t)0 * KK + (KT) * 64,   &BL[DD][0][tid * 8]);         \
    glds16(Bbase + (size_t)64 * KK + (KT) * 64,  &BL[DD][0][4096 + tid * 8]);  \
    glds16(Bbase + (size_t)128 * KK + (KT) * 64, &BL[DD][1][tid * 8]);         \
    glds16(Bbase + (size_t)192 * KK + (KT) * 64, &BL[DD][1][4096 + tid * 8]);  \
  } while (0)

#define LGKM12() asm volatile("s_waitcnt lgkmcnt(12)" ::: "memory")
#define LGKM0()  asm volatile("s_waitcnt lgkmcnt(0)" ::: "memory")
#define VMC8()   asm volatile("s_waitcnt vmcnt(8)" ::: "memory")
#define VMC0()   asm volatile("s_waitcnt vmcnt(0)" ::: "memory")
#define FENCE()  asm volatile("" ::: "memory")

#define LDA(D, M, KH) (*(const short8v*)&AL[D][wr][((M) * 16 + l15) * 64 + ((KH) ? ss1 : ss0)])
#define LDB(D, N, KH) (*(const short8v*)&BL[D][bhalf][(brow0 + (N) * 16) * 64 + ((KH) ? ss1 : ss0)])
#define LD_A03(D) do { _Pragma("unroll") for (int q = 0; q < 4; ++q) { \
    a03[q][0] = LDA(D, q, 0); a03[q][1] = LDA(D, q, 1); } } while (0)
#define LD_A47(D) do { _Pragma("unroll") for (int q = 0; q < 4; ++q) { \
    a47[q][0] = LDA(D, q + 4, 0); a47[q][1] = LDA(D, q + 4, 1); } } while (0)
#define LD_B01(D) do { _Pragma("unroll") for (int n = 0; n < 2; ++n) { \
    b01[n][0] = LDB(D, n, 0); b01[n][1] = LDB(D, n, 1); } } while (0)
#define LD_B23(D) do { _Pragma("unroll") for (int n = 0; n < 2; ++n) { \
    b23[n][0] = LDB(D, n + 2, 0); b23[n][1] = LDB(D, n + 2, 1); } } while (0)

#define MFMA1(a, b, c) c = __builtin_amdgcn_mfma_f32_16x16x32_bf16(a, b, c, 0, 0, 0)
#define CL16(AR, BR, MS, NS)                                                   \
  do {                                                                         \
    if (DO_S) __builtin_amdgcn_s_setprio(1);                                   \
    _Pragma("unroll")                                                          \
    for (int q = 0; q < 4; ++q) {                                              \
      MFMA1(AR[q][0], BR[0][0], acc[(MS) * 4 + q][(NS) * 2]);                  \
      MFMA1(AR[q][0], BR[1][0], acc[(MS) * 4 + q][(NS) * 2 + 1]);              \
      MFMA1(AR[q][1], BR[0][1], acc[(MS) * 4 + q][(NS) * 2]);                  \
      MFMA1(AR[q][1], BR[1][1], acc[(MS) * 4 + q][(NS) * 2 + 1]);              \
    }                                                                          \
    if (DO_S) __builtin_amdgcn_s_setprio(0);                                   \
  } while (0)

  // ---- prologue: stage tiles 0,1; wait tile 0; first R1 reads ----
  if (DO_G) { STAGE(0, 0); STAGE(1, 1); }
  if (DO_S) { VMC8(); FENCE(); __builtin_amdgcn_s_barrier(); FENCE(); }
  LD_A03(0); LD_B01(0);
  if (V >= 2) { LD_A47(0); LD_B23(0); LGKM0(); }   // V2/V3: operands fixed once

  for (int t = 0; t < 16; ++t) {
    const int d = t & 1, dn = d ^ 1;
    const int kt2 = (t + 2) & 15;    // wrap staging keeps vmcnt counts uniform

    if (DO_D) { LD_A47(d); LD_B23(d); }   // R2(t): 12 reads
    if (DO_S && DO_D) LGKM12();           // R1(t) complete (in-order DS retire)
    CL16(a03, b01, 0, 0);                 // Q1 overlaps R2 service

    if (DO_S && DO_D) LGKM0();            // R2(t) complete
    CL16(a03, b23, 0, 1);                 // Q2; a03 dead after

    if (DO_S) VMC0();                     // S(t+1) landed (issued 1 tile ago)
    if (DO_D) LD_A03(dn);                 // R1(t+1) part 1: flies under Q3/Q4
    CL16(a47, b01, 1, 0);                 // Q3; b01 dead after
    if (DO_D) LD_B01(dn);                 // R1(t+1) part 2

    if (DO_S) { FENCE(); __builtin_amdgcn_s_barrier(); FENCE(); }
    if (DO_G) STAGE(d, kt2);              // S(t+2) -> d: WAR-safe post-barrier
    CL16(a47, b23, 1, 1);                 // Q4 overlaps stage issue + R1 service
  }

#undef CL16
#undef MFMA1
#undef LD_A03
#undef LD_A47
#undef LD_B01
#undef LD_B23
#undef LDA
#undef LDB
#undef FENCE
#undef VMC0
#undef VMC8
#undef LGKM0
#undef LGKM12
#undef STAGE

  // ---- epilogue: masked (strictly below anchor, off-diagonal) row/col max ----
  // C/D layout: col = lane&15, row = (lane>>4)*4 + reg
  const int rbase = bi * 256 + wr * 128;
  const int cbase = bj * 256 + wc * 64;

  float ar[32], ac[4];
#pragma unroll
  for (int m = 0; m < 8; ++m)
#pragma unroll
    for (int r = 0; r < 4; ++r)
      ar[m * 4 + r] = anchor[rbase + m * 16 + l4 * 4 + r];
#pragma unroll
  for (int n = 0; n < 4; ++n)
    ac[n] = anchor[cbase + n * 16 + l15];

#pragma unroll
  for (int m = 0; m < 8; ++m) {
#pragma unroll
    for (int r = 0; r < 4; ++r) {
      const int rg = rbase + m * 16 + l4 * 4 + r;
      const float a = ar[m * 4 + r];
      uint32_t e = 0;
#pragma unroll
      for (int n = 0; n < 4; ++n) {
        const int cg = cbase + n * 16 + l15;
        float v = acc[m][n][r];
        if (v < a && rg != cg) { uint32_t fe = fenc(v); e = (fe > e) ? fe : e; }
      }
#pragma unroll
      for (int sh = 1; sh < 16; sh <<= 1) {
        uint32_t o = (uint32_t)__shfl_xor((int)e, sh, 64);
        e = (o > e) ? o : e;
      }
      if (l15 == 0 && e) atomicMax(&rowmax[rg], e);
    }
  }
#pragma unroll
  for (int n = 0; n < 4; ++n) {
    const int cg = cbase + n * 16 + l15;
    const float a = ac[n];
    uint32_t e = 0;
#pragma unroll
    for (int m = 0; m < 8; ++m) {
#pragma unroll
      for (int r = 0; r < 4; ++r) {
        const int rg = rbase + m * 16 + l4 * 4 + r;
        float v = acc[m][n][r];
        if (v < a && rg != cg) { uint32_t fe = fenc(v); e = (fe > e) ? fe : e; }
      }
    }
    {
      uint32_t o = (uint32_t)__shfl_xor((int)e, 16, 64); e = (o > e) ? o : e;
      o = (uint32_t)__shfl_xor((int)e, 32, 64);          e = (o > e) ? o : e;
    }
    if (l4 == 0 && e) atomicMax(&colmax[cg], e);
  }
}

// ---------------- Kernel 4: hinge terms + mean -------------------------------
__global__ __launch_bounds__(256) void k_final(
    const float* __restrict__ anchor,
    const float* __restrict__ irr, const float* __restrict__ irf,
    const float* __restrict__ icr, const float* __restrict__ icf,
    const uint32_t* __restrict__ rowmax, const uint32_t* __restrict__ colmax,
    float* __restrict__ out) {
  float s = 0.f;
  for (int k = (int)threadIdx.x; k < NN; k += 256) {
    float a = anchor[k];
    float d1 = fmaxf(irr[k] - a + 1.0f, 0.f);
    uint32_t rm = rowmax[k];
    float imp2r = rm ? fdec(rm) : irf[k];
    float d2 = fmaxf(imp2r - a + 1.0f, 0.f);
    float e1 = fmaxf(icr[k] - a + 1.0f, 0.f);
    uint32_t cm = colmax[k];
    float imp2c = cm ? fdec(cm) : icf[k];
    float e2 = fmaxf(imp2c - a + 1.0f, 0.f);
    s += d1 + d2 + e1 + e2;
  }
  __shared__ float red[4];
  for (int m = 32; m >= 1; m >>= 1) s += __shfl_xor(s, m);
  if ((threadIdx.x & 63) == 0) red[threadIdx.x >> 6] = s;
  __syncthreads();
  if (threadIdx.x == 0) out[0] = (red[0] + red[1] + red[2] + red[3]) * (1.0f / NN);
}

// -----------------------------------------------------------------------------
extern "C" void kernel_launch(void* const* d_in, const int* in_sizes, int n_in,
                              void* d_out, int out_size, void* d_ws, size_t ws_size,
                              hipStream_t stream) {
  const float* X = (const float*)d_in[0];
  const float* Y = (const float*)d_in[1];
  float* out = (float*)d_out;

  char* ws = (char*)d_ws;
  float* anchor    = (float*)(ws + 0 * 16384);
  float* irr       = (float*)(ws + 1 * 16384);
  float* irf       = (float*)(ws + 2 * 16384);
  float* icr       = (float*)(ws + 3 * 16384);
  float* icf       = (float*)(ws + 4 * 16384);
  uint32_t* rowmax = (uint32_t*)(ws + 5 * 16384);
  uint32_t* colmax = (uint32_t*)(ws + 6 * 16384);
  uint32_t* dum_r  = (uint32_t*)(ws + 7 * 16384);   // ablation scratch
  uint32_t* dum_c  = (uint32_t*)(ws + 8 * 16384);
  ushort_t* Xb     = (ushort_t*)(ws + 256 * 1024);
  ushort_t* Yb     = Xb + (size_t)NN * KK;

  // subkeys = split(key(42), 4), partitionable: sk_i = threefry((0,42),(0,i))
  uint32_t sk[4][2];
  for (int i = 0; i < 4; ++i) tf2x32(0u, 42u, 0u, (uint32_t)i, &sk[i][0], &sk[i][1]);

  k_prep<<<4096, 256, 0, stream>>>((const float4*)X, (const float4*)Y,
                                   (ushort4*)Xb, (ushort4*)Yb, rowmax, colmax);

  k_dots<<<NN / 4, 256, 0, stream>>>(X, Y,
      sk[0][0], sk[0][1], sk[1][0], sk[1][1], sk[2][0], sk[2][1], sk[3][0], sk[3][1],
      anchor, irr, irf, icr, icf);

  // V0 = real result; V1/V2/V3 = ablation probes into scratch tables
  k_gemm_pl<0><<<256, 512, 0, stream>>>(Xb, Yb, anchor, rowmax, colmax);
  k_gemm_pl<1><<<256, 512, 0, stream>>>(Xb, Yb, anchor, dum_r, dum_c);
  k_gemm_pl<2><<<256, 512, 0, stream>>>(Xb, Yb, anchor, dum_r, dum_c);
  k_gemm_pl<3><<<256, 512, 0, stream>>>(Xb, Yb, anchor, dum_r, dum_c);

  k_final<<<1, 256, 0, stream>>>(anchor, irr, irf, icr, icf, rowmax, colmax, out);
}

// Round 7
// 105.509 us; speedup vs baseline: 2.1576x; 2.1576x over previous
//
#include <hip/hip_runtime.h>
#include <stdint.h>
#include <stddef.h>

#define NN 4096
#define KK 1024
#define SPAN 4095u

typedef unsigned short ushort_t;
typedef __attribute__((ext_vector_type(8))) short short8v;   // 8 bf16 = 4 VGPR
typedef __attribute__((ext_vector_type(4))) float f32x4;     // MFMA C/D

// ---------------- Threefry-2x32, 20 rounds (exact JAX algorithm) -------------
__host__ __device__ inline void tf2x32(uint32_t k0, uint32_t k1,
                                       uint32_t x0, uint32_t x1,
                                       uint32_t* o0, uint32_t* o1) {
  uint32_t ks2 = k0 ^ k1 ^ 0x1BD11BDAu;
  uint32_t v0 = x0 + k0;
  uint32_t v1 = x1 + k1;
#define TF_ROT(x, r) (((x) << (r)) | ((x) >> (32 - (r))))
#define TF_RND(r) do { v0 += v1; v1 = TF_ROT(v1, r); v1 ^= v0; } while (0)
  TF_RND(13); TF_RND(15); TF_RND(26); TF_RND(6);
  v0 += k1;  v1 += ks2 + 1u;
  TF_RND(17); TF_RND(29); TF_RND(16); TF_RND(24);
  v0 += ks2; v1 += k0 + 2u;
  TF_RND(13); TF_RND(15); TF_RND(26); TF_RND(6);
  v0 += k0;  v1 += k1 + 3u;
  TF_RND(17); TF_RND(29); TF_RND(16); TF_RND(24);
  v0 += k1;  v1 += ks2 + 4u;
  TF_RND(13); TF_RND(15); TF_RND(26); TF_RND(6);
  v0 += ks2; v1 += k0 + 5u;
#undef TF_RND
#undef TF_ROT
  *o0 = v0; *o1 = v1;
}

__device__ inline uint32_t rb32(uint32_t ka, uint32_t kb, uint32_t i) {
  uint32_t a, b;
  tf2x32(ka, kb, 0u, i, &a, &b);
  return a ^ b;
}

// Monotone order-preserving float<->uint32 encoding; 0 == "no candidate".
__device__ inline uint32_t fenc(float f) {
  uint32_t b = __float_as_uint(f);
  return (b & 0x80000000u) ? ~b : (b | 0x80000000u);
}
__device__ inline float fdec(uint32_t e) {
  uint32_t b = (e & 0x80000000u) ? (e & 0x7FFFFFFFu) : ~e;
  return __uint_as_float(b);
}

__device__ inline ushort_t bf16rne(float f) {   // fp32 -> bf16 round-nearest-even
  uint32_t u = __float_as_uint(f);
  return (ushort_t)((u + 0x7FFFu + ((u >> 16) & 1u)) >> 16);
}

__device__ inline void glds16(const void* g, void* l) {
  __builtin_amdgcn_global_load_lds((const __attribute__((address_space(1))) void*)g,
                                   (__attribute__((address_space(3))) void*)l, 16, 0, 0);
}

// ---------------- Kernel 1: fp32->bf16 convert for X,Y + zero max tables -----
__global__ __launch_bounds__(256) void k_prep(
    const float4* __restrict__ X, const float4* __restrict__ Y,
    ushort4* __restrict__ Xb, ushort4* __restrict__ Yb,
    uint32_t* __restrict__ rowmax, uint32_t* __restrict__ colmax) {
  const int b = blockIdx.x, tid = threadIdx.x;
  if (b < 16) rowmax[b * 256 + tid] = 0u;
  else if (b < 32) colmax[(b - 16) * 256 + tid] = 0u;
  const float4* src = (b < 2048) ? X : Y;
  ushort4* dst = (b < 2048) ? Xb : Yb;
  const int n4 = NN * KK / 4;
  for (int i = (b & 2047) * 256 + tid; i < n4; i += 2048 * 256) {
    float4 v = src[i];
    ushort4 o;
    o.x = bf16rne(v.x); o.y = bf16rne(v.y); o.z = bf16rne(v.z); o.w = bf16rne(v.w);
    dst[i] = o;
  }
}

// ---------------- Kernel 2: anchors + 4 gathered imposter dots (inline PRNG) -
__global__ __launch_bounds__(256) void k_dots(
    const float* __restrict__ X, const float* __restrict__ Y,
    uint32_t s0a, uint32_t s0b, uint32_t s1a, uint32_t s1b,
    uint32_t s2a, uint32_t s2b, uint32_t s3a, uint32_t s3b,
    float* __restrict__ anchor, float* __restrict__ irr, float* __restrict__ irf,
    float* __restrict__ icr, float* __restrict__ icf) {
  const int wid = threadIdx.x >> 6;
  const int lane = threadIdx.x & 63;
  const int row = blockIdx.x * 4 + wid;

  int jl = 0;
  if (lane < 4) {
    uint32_t ka = (lane == 0) ? s0a : (lane == 1) ? s1a : (lane == 2) ? s2a : s3a;
    uint32_t kb = (lane == 0) ? s0b : (lane == 1) ? s1b : (lane == 2) ? s2b : s3b;
    uint32_t k1a, k1b, k2a, k2b;
    tf2x32(ka, kb, 0u, 0u, &k1a, &k1b);
    tf2x32(ka, kb, 0u, 1u, &k2a, &k2b);
    uint32_t hi = rb32(k1a, k1b, (uint32_t)row);
    uint32_t lo = rb32(k2a, k2b, (uint32_t)row);
    uint32_t off = ((hi % SPAN) * 256u + (lo % SPAN)) % SPAN;
    int j = (int)off;
    jl = j + ((j >= row) ? 1 : 0);
  }
  const int j1r = __shfl(jl, 0), j1f = __shfl(jl, 1);
  const int j2r = __shfl(jl, 2), j2f = __shfl(jl, 3);

  const float4* xk = (const float4*)(X + (size_t)row * KK);
  const float4* yk = (const float4*)(Y + (size_t)row * KK);
  const float4* y1 = (const float4*)(Y + (size_t)j1r * KK);
  const float4* y2 = (const float4*)(Y + (size_t)j1f * KK);
  const float4* x1 = (const float4*)(X + (size_t)j2r * KK);
  const float4* x2 = (const float4*)(X + (size_t)j2f * KK);
  float sa = 0.f, s1 = 0.f, s2 = 0.f, s3 = 0.f, s4 = 0.f;
  for (int t = lane; t < KK / 4; t += 64) {
    float4 xv = xk[t], yv = yk[t], a1 = y1[t], a2 = y2[t], b1 = x1[t], b2 = x2[t];
    sa = fmaf(xv.x, yv.x, fmaf(xv.y, yv.y, fmaf(xv.z, yv.z, fmaf(xv.w, yv.w, sa))));
    s1 = fmaf(xv.x, a1.x, fmaf(xv.y, a1.y, fmaf(xv.z, a1.z, fmaf(xv.w, a1.w, s1))));
    s2 = fmaf(xv.x, a2.x, fmaf(xv.y, a2.y, fmaf(xv.z, a2.z, fmaf(xv.w, a2.w, s2))));
    s3 = fmaf(b1.x, yv.x, fmaf(b1.y, yv.y, fmaf(b1.z, yv.z, fmaf(b1.w, yv.w, s3))));
    s4 = fmaf(b2.x, yv.x, fmaf(b2.y, yv.y, fmaf(b2.z, yv.z, fmaf(b2.w, yv.w, s4))));
  }
  for (int m = 32; m >= 1; m >>= 1) {
    sa += __shfl_xor(sa, m);
    s1 += __shfl_xor(s1, m);
    s2 += __shfl_xor(s2, m);
    s3 += __shfl_xor(s3, m);
    s4 += __shfl_xor(s4, m);
  }
  if (lane == 0) {
    anchor[row] = sa; irr[row] = s1; irf[row] = s2; icr[row] = s3; icf[row] = s4;
  }
}

// ------ Kernel 3: m97-replica 128x128 MFMA GEMM + fused masked row/col max ---
// 128^2 tile, BK=32, 4 waves (2x2 of 64x64), 32 KB LDS -> 2+ blocks/CU so
// cross-block waves hide each other's barrier/vmcnt stalls (m114 mechanism).
// LINEAR LDS both sides (rule 21 trivially satisfied): at BK=32 the fragment
// read granules (m*16+l15)*4 + l4 are 64 consecutive 16B granules ->
// inherently bank-conflict-free; no swizzle, no inline asm, no sched_barrier,
// no setprio -- compiler emits its own fine-grained lgkmcnt (m97 mode).

__global__ __launch_bounds__(256, 2) void k_gemm97(
    const ushort_t* __restrict__ A, const ushort_t* __restrict__ B,
    const float* __restrict__ anchor,
    uint32_t* __restrict__ rowmax, uint32_t* __restrict__ colmax) {
  __shared__ ushort_t AL[2][4096];   // [buf][128 rows x 32 k]
  __shared__ ushort_t BL[2][4096];

  const int tid = threadIdx.x;
  const int lane = tid & 63;
  const int w = tid >> 6, wr = w >> 1, wc = w & 1;   // 2x2 waves, 64x64 each
  const int l15 = lane & 15, l4 = lane >> 4;

  // T1: XCD-aware bijective swizzle (1024 blocks % 8 == 0)
  const int swz = (blockIdx.x & 7) * 128 + (blockIdx.x >> 3);
  const int bi = swz >> 5, bj = swz & 31;

  // staging: thread t covers rows (t>>2) and (t>>2)+64, 16B slot t&3 (linear)
  const int strow = tid >> 2, scol = (tid & 3) * 8;
  const ushort_t* Asrc = A + (size_t)(bi * 128 + strow) * KK + scol;
  const ushort_t* Bsrc = B + (size_t)(bj * 128 + strow) * KK + scol;

  const int aoff = (wr * 64 + l15) * 32 + l4 * 8;    // + m*16*32 per frag
  const int boff = (wc * 64 + l15) * 32 + l4 * 8;

  f32x4 acc[4][4] = {};

  glds16(Asrc,           &AL[0][tid * 8]);
  glds16(Asrc + 64 * KK, &AL[0][2048 + tid * 8]);
  glds16(Bsrc,           &BL[0][tid * 8]);
  glds16(Bsrc + 64 * KK, &BL[0][2048 + tid * 8]);
  __syncthreads();

  for (int t = 0; t < 32; ++t) {
    const int buf = t & 1;
    if (t < 31) {
      const size_t kk = (size_t)(t + 1) * 32;
      glds16(Asrc + kk,           &AL[buf ^ 1][tid * 8]);
      glds16(Asrc + 64 * KK + kk, &AL[buf ^ 1][2048 + tid * 8]);
      glds16(Bsrc + kk,           &BL[buf ^ 1][tid * 8]);
      glds16(Bsrc + 64 * KK + kk, &BL[buf ^ 1][2048 + tid * 8]);
    }
    short8v af[4], bf[4];
#pragma unroll
    for (int m = 0; m < 4; ++m) af[m] = *(const short8v*)&AL[buf][aoff + m * 512];
#pragma unroll
    for (int n = 0; n < 4; ++n) bf[n] = *(const short8v*)&BL[buf][boff + n * 512];
#pragma unroll
    for (int m = 0; m < 4; ++m)
#pragma unroll
      for (int n = 0; n < 4; ++n)
        acc[m][n] = __builtin_amdgcn_mfma_f32_16x16x32_bf16(af[m], bf[n], acc[m][n], 0, 0, 0);
    __syncthreads();   // protects buf for overwrite next iter + drains glds(buf^1)
  }

  // ---- epilogue: masked (strictly below anchor, off-diagonal) row/col max ----
  // C/D layout: col = lane&15, row = (lane>>4)*4 + reg  (r2-verified epilogue)
  const int rbase = bi * 128 + wr * 64;
  const int cbase = bj * 128 + wc * 64;

  float ar[16], ac[4];
#pragma unroll
  for (int m = 0; m < 4; ++m)
#pragma unroll
    for (int r = 0; r < 4; ++r)
      ar[m * 4 + r] = anchor[rbase + m * 16 + l4 * 4 + r];
#pragma unroll
  for (int n = 0; n < 4; ++n)
    ac[n] = anchor[cbase + n * 16 + l15];

  // row maxima: same row across lanes sharing l4 -> reduce over l15 (xor 1,2,4,8)
#pragma unroll
  for (int m = 0; m < 4; ++m) {
#pragma unroll
    for (int r = 0; r < 4; ++r) {
      const int rg = rbase + m * 16 + l4 * 4 + r;
      const float a = ar[m * 4 + r];
      uint32_t e = 0;
#pragma unroll
      for (int n = 0; n < 4; ++n) {
        const int cg = cbase + n * 16 + l15;
        float v = acc[m][n][r];
        if (v < a && rg != cg) { uint32_t fe = fenc(v); e = (fe > e) ? fe : e; }
      }
#pragma unroll
      for (int sh = 1; sh < 16; sh <<= 1) {
        uint32_t o = (uint32_t)__shfl_xor((int)e, sh, 64);
        e = (o > e) ? o : e;
      }
      if (l15 == 0 && e) atomicMax(&rowmax[rg], e);
    }
  }
  // col maxima: same col across lanes sharing l15 -> reduce over l4 (xor 16,32)
#pragma unroll
  for (int n = 0; n < 4; ++n) {
    const int cg = cbase + n * 16 + l15;
    const float a = ac[n];
    uint32_t e = 0;
#pragma unroll
    for (int m = 0; m < 4; ++m) {
#pragma unroll
      for (int r = 0; r < 4; ++r) {
        const int rg = rbase + m * 16 + l4 * 4 + r;
        float v = acc[m][n][r];
        if (v < a && rg != cg) { uint32_t fe = fenc(v); e = (fe > e) ? fe : e; }
      }
    }
    {
      uint32_t o = (uint32_t)__shfl_xor((int)e, 16, 64); e = (o > e) ? o : e;
      o = (uint32_t)__shfl_xor((int)e, 32, 64);          e = (o > e) ? o : e;
    }
    if (l4 == 0 && e) atomicMax(&colmax[cg], e);
  }
}

// ---------------- Kernel 4: hinge terms + mean -------------------------------
__global__ __launch_bounds__(256) void k_final(
    const float* __restrict__ anchor,
    const float* __restrict__ irr, const float* __restrict__ irf,
    const float* __restrict__ icr, const float* __restrict__ icf,
    const uint32_t* __restrict__ rowmax, const uint32_t* __restrict__ colmax,
    float* __restrict__ out) {
  float s = 0.f;
  for (int k = (int)threadIdx.x; k < NN; k += 256) {
    float a = anchor[k];
    float d1 = fmaxf(irr[k] - a + 1.0f, 0.f);
    uint32_t rm = rowmax[k];
    float imp2r = rm ? fdec(rm) : irf[k];
    float d2 = fmaxf(imp2r - a + 1.0f, 0.f);
    float e1 = fmaxf(icr[k] - a + 1.0f, 0.f);
    uint32_t cm = colmax[k];
    float imp2c = cm ? fdec(cm) : icf[k];
    float e2 = fmaxf(imp2c - a + 1.0f, 0.f);
    s += d1 + d2 + e1 + e2;
  }
  __shared__ float red[4];
  for (int m = 32; m >= 1; m >>= 1) s += __shfl_xor(s, m);
  if ((threadIdx.x & 63) == 0) red[threadIdx.x >> 6] = s;
  __syncthreads();
  if (threadIdx.x == 0) out[0] = (red[0] + red[1] + red[2] + red[3]) * (1.0f / NN);
}

// -----------------------------------------------------------------------------
extern "C" void kernel_launch(void* const* d_in, const int* in_sizes, int n_in,
                              void* d_out, int out_size, void* d_ws, size_t ws_size,
                              hipStream_t stream) {
  const float* X = (const float*)d_in[0];
  const float* Y = (const float*)d_in[1];
  float* out = (float*)d_out;

  char* ws = (char*)d_ws;
  float* anchor    = (float*)(ws + 0 * 16384);
  float* irr       = (float*)(ws + 1 * 16384);
  float* irf       = (float*)(ws + 2 * 16384);
  float* icr       = (float*)(ws + 3 * 16384);
  float* icf       = (float*)(ws + 4 * 16384);
  uint32_t* rowmax = (uint32_t*)(ws + 5 * 16384);
  uint32_t* colmax = (uint32_t*)(ws + 6 * 16384);
  ushort_t* Xb     = (ushort_t*)(ws + 256 * 1024);
  ushort_t* Yb     = Xb + (size_t)NN * KK;

  // subkeys = split(key(42), 4), partitionable: sk_i = threefry((0,42),(0,i))
  uint32_t sk[4][2];
  for (int i = 0; i < 4; ++i) tf2x32(0u, 42u, 0u, (uint32_t)i, &sk[i][0], &sk[i][1]);

  k_prep<<<4096, 256, 0, stream>>>((const float4*)X, (const float4*)Y,
                                   (ushort4*)Xb, (ushort4*)Yb, rowmax, colmax);

  k_dots<<<NN / 4, 256, 0, stream>>>(X, Y,
      sk[0][0], sk[0][1], sk[1][0], sk[1][1], sk[2][0], sk[2][1], sk[3][0], sk[3][1],
      anchor, irr, irf, icr, icf);

  k_gemm97<<<1024, 256, 0, stream>>>(Xb, Yb, anchor, rowmax, colmax);

  k_final<<<1, 256, 0, stream>>>(anchor, irr, irf, icr, icf, rowmax, colmax, out);
}

// Round 8
// 93.633 us; speedup vs baseline: 2.4312x; 1.1268x over previous
//
#include <hip/hip_runtime.h>
#include <stdint.h>
#include <stddef.h>

#define NN 4096
#define KK 1024
#define SPAN 4095u

typedef unsigned short ushort_t;
typedef __attribute__((ext_vector_type(8))) short short8v;   // 8 bf16 = 4 VGPR
typedef __attribute__((ext_vector_type(4))) float f32x4;     // MFMA C/D

// ---------------- Threefry-2x32, 20 rounds (exact JAX algorithm) -------------
__host__ __device__ inline void tf2x32(uint32_t k0, uint32_t k1,
                                       uint32_t x0, uint32_t x1,
                                       uint32_t* o0, uint32_t* o1) {
  uint32_t ks2 = k0 ^ k1 ^ 0x1BD11BDAu;
  uint32_t v0 = x0 + k0;
  uint32_t v1 = x1 + k1;
#define TF_ROT(x, r) (((x) << (r)) | ((x) >> (32 - (r))))
#define TF_RND(r) do { v0 += v1; v1 = TF_ROT(v1, r); v1 ^= v0; } while (0)
  TF_RND(13); TF_RND(15); TF_RND(26); TF_RND(6);
  v0 += k1;  v1 += ks2 + 1u;
  TF_RND(17); TF_RND(29); TF_RND(16); TF_RND(24);
  v0 += ks2; v1 += k0 + 2u;
  TF_RND(13); TF_RND(15); TF_RND(26); TF_RND(6);
  v0 += k0;  v1 += k1 + 3u;
  TF_RND(17); TF_RND(29); TF_RND(16); TF_RND(24);
  v0 += k1;  v1 += ks2 + 4u;
  TF_RND(13); TF_RND(15); TF_RND(26); TF_RND(6);
  v0 += ks2; v1 += k0 + 5u;
#undef TF_RND
#undef TF_ROT
  *o0 = v0; *o1 = v1;
}

__device__ inline uint32_t rb32(uint32_t ka, uint32_t kb, uint32_t i) {
  uint32_t a, b;
  tf2x32(ka, kb, 0u, i, &a, &b);
  return a ^ b;
}

// Monotone order-preserving float<->uint32 encoding; 0 == "no candidate".
__device__ inline uint32_t fenc(float f) {
  uint32_t b = __float_as_uint(f);
  return (b & 0x80000000u) ? ~b : (b | 0x80000000u);
}
__device__ inline float fdec(uint32_t e) {
  uint32_t b = (e & 0x80000000u) ? (e & 0x7FFFFFFFu) : ~e;
  return __uint_as_float(b);
}

__device__ inline ushort_t bf16rne(float f) {   // fp32 -> bf16 round-nearest-even
  uint32_t u = __float_as_uint(f);
  return (ushort_t)((u + 0x7FFFu + ((u >> 16) & 1u)) >> 16);
}
__device__ inline float bf2f(ushort_t v) {
  return __uint_as_float(((uint32_t)v) << 16);
}

__device__ inline void glds16(const void* g, void* l) {
  __builtin_amdgcn_global_load_lds((const __attribute__((address_space(1))) void*)g,
                                   (__attribute__((address_space(3))) void*)l, 16, 0, 0);
}

// ---------------- Kernel 1: fp32->bf16 convert for X,Y + zero max tables -----
__global__ __launch_bounds__(256) void k_prep(
    const float4* __restrict__ X, const float4* __restrict__ Y,
    ushort4* __restrict__ Xb, ushort4* __restrict__ Yb,
    uint32_t* __restrict__ rowmax, uint32_t* __restrict__ colmax) {
  const int b = blockIdx.x, tid = threadIdx.x;
  if (b < 16) rowmax[b * 256 + tid] = 0u;
  else if (b < 32) colmax[(b - 16) * 256 + tid] = 0u;
  const float4* src = (b < 2048) ? X : Y;
  ushort4* dst = (b < 2048) ? Xb : Yb;
  const int n4 = NN * KK / 4;
  for (int i = (b & 2047) * 256 + tid; i < n4; i += 2048 * 256) {
    float4 v = src[i];
    ushort4 o;
    o.x = bf16rne(v.x); o.y = bf16rne(v.y); o.z = bf16rne(v.z); o.w = bf16rne(v.w);
    dst[i] = o;
  }
}

// --------- Kernel 2: anchors + 4 gathered imposter dots (bf16 inputs) --------
__global__ __launch_bounds__(256) void k_dots(
    const ushort_t* __restrict__ Xb, const ushort_t* __restrict__ Yb,
    uint32_t s0a, uint32_t s0b, uint32_t s1a, uint32_t s1b,
    uint32_t s2a, uint32_t s2b, uint32_t s3a, uint32_t s3b,
    float* __restrict__ anchor, float* __restrict__ irr, float* __restrict__ irf,
    float* __restrict__ icr, float* __restrict__ icf) {
  const int wid = threadIdx.x >> 6;
  const int lane = threadIdx.x & 63;
  const int row = blockIdx.x * 4 + wid;

  int jl = 0;
  if (lane < 4) {
    uint32_t ka = (lane == 0) ? s0a : (lane == 1) ? s1a : (lane == 2) ? s2a : s3a;
    uint32_t kb = (lane == 0) ? s0b : (lane == 1) ? s1b : (lane == 2) ? s2b : s3b;
    uint32_t k1a, k1b, k2a, k2b;
    tf2x32(ka, kb, 0u, 0u, &k1a, &k1b);
    tf2x32(ka, kb, 0u, 1u, &k2a, &k2b);
    uint32_t hi = rb32(k1a, k1b, (uint32_t)row);
    uint32_t lo = rb32(k2a, k2b, (uint32_t)row);
    uint32_t off = ((hi % SPAN) * 256u + (lo % SPAN)) % SPAN;
    int j = (int)off;
    jl = j + ((j >= row) ? 1 : 0);
  }
  const int j1r = __shfl(jl, 0), j1f = __shfl(jl, 1);
  const int j2r = __shfl(jl, 2), j2f = __shfl(jl, 3);

  const short8v* xk = (const short8v*)(Xb + (size_t)row * KK);
  const short8v* yk = (const short8v*)(Yb + (size_t)row * KK);
  const short8v* y1 = (const short8v*)(Yb + (size_t)j1r * KK);
  const short8v* y2 = (const short8v*)(Yb + (size_t)j1f * KK);
  const short8v* x1 = (const short8v*)(Xb + (size_t)j2r * KK);
  const short8v* x2 = (const short8v*)(Xb + (size_t)j2f * KK);
  float sa = 0.f, s1 = 0.f, s2 = 0.f, s3 = 0.f, s4 = 0.f;
  for (int t = lane; t < KK / 8; t += 64) {
    short8v xv = xk[t], yv = yk[t], a1 = y1[t], a2 = y2[t], b1 = x1[t], b2 = x2[t];
#pragma unroll
    for (int j = 0; j < 8; ++j) {
      float xf = bf2f((ushort_t)xv[j]), yf = bf2f((ushort_t)yv[j]);
      sa = fmaf(xf, yf, sa);
      s1 = fmaf(xf, bf2f((ushort_t)a1[j]), s1);
      s2 = fmaf(xf, bf2f((ushort_t)a2[j]), s2);
      s3 = fmaf(bf2f((ushort_t)b1[j]), yf, s3);
      s4 = fmaf(bf2f((ushort_t)b2[j]), yf, s4);
    }
  }
  for (int m = 32; m >= 1; m >>= 1) {
    sa += __shfl_xor(sa, m);
    s1 += __shfl_xor(s1, m);
    s2 += __shfl_xor(s2, m);
    s3 += __shfl_xor(s3, m);
    s4 += __shfl_xor(s4, m);
  }
  if (lane == 0) {
    anchor[row] = sa; irr[row] = s1; irf[row] = s2; icr[row] = s3; icf[row] = s4;
  }
}

// -- Kernel 3: 256x256 GEMM, CROSS-PHASE register-pipelined 4-phase schedule --
// Per K-tile (BK=64, buf d=u&1): 4 phases (mh,kh) = (0,0),(1,0),(0,1),(1,1),
// 16 MFMA each. Phase p ISSUES ds_reads for phase p+1's operands into the
// alternate reg set, then s_barrier, then MFMA on regs read at p-1 -- so DS
// service overlaps the previous MFMA cluster + barrier (the m196/m201 fine
// interleave). No hand lgkmcnt: reads are compiler-visible, it emits minimal
// counted waits. Raw s_barrier (no vmcnt(0) drain).
// Staging (region free exactly one phase after its last read drains):
//   ph0: stage_A(buf dn, tile u+1)   [A-region dn last read: prev-tile ph2,
//                                     drained prev ph3, sealed by its barrier]
//   ph3: stage_B(buf d,  tile u+2)   [B-region d last read: ph1, drained ph2]
// Gate: asm vmcnt(0)+barrier at ph2 end -- outstanding there are exactly the
// 8 loads of tile u+1 (A@ph0, B@prev-ph3), issued >=2.5 phases (~1700cy) ago.
// Swizzle, staging maps, epilogue identical to r5 (absmax 0.0 verified).

__global__ __launch_bounds__(512, 2) void k_gemm_xp(
    const ushort_t* __restrict__ A, const ushort_t* __restrict__ B,
    const float* __restrict__ anchor,
    uint32_t* __restrict__ rowmax, uint32_t* __restrict__ colmax) {
  __shared__ ushort_t AL[2][2][8192];   // [dbuf][half][128 rows x 64 k]
  __shared__ ushort_t BL[2][2][8192];

  const int tid = threadIdx.x;
  const int lane = tid & 63;
  const int w = tid >> 6, wr = w >> 2, wc = w & 3;   // 8 waves: 2M x 4N
  const int l15 = lane & 15, l4 = lane >> 4;

  // T1: XCD-aware bijective swizzle (256 blocks % 8 == 0)
  const int swz = (blockIdx.x & 7) * 32 + (blockIdx.x >> 3);
  const int bi = swz >> 4, bj = swz & 15;

  const int strow = tid >> 3;
  const int scol = ((tid & 7) ^ (strow & 7)) * 8;
  const ushort_t* Abase = A + (size_t)(bi * 256 + strow) * KK + scol;
  const ushort_t* Bbase = B + (size_t)(bj * 256 + strow) * KK + scol;

  const int ss0 = ((0 * 4 + l4) ^ (l15 & 7)) * 8;
  const int ss1 = ((1 * 4 + l4) ^ (l15 & 7)) * 8;
  const int bhalf = wc >> 1, brow0 = (wc & 1) * 64 + l15;

  f32x4 acc[8][4] = {};
  short8v aR[2][4], bR[2][4];

#define STAGE_A(DD, KT)                                                        \
  do {                                                                         \
    glds16(Abase + (size_t)0 * KK + (KT) * 64,   &AL[DD][0][tid * 8]);         \
    glds16(Abase + (size_t)64 * KK + (KT) * 64,  &AL[DD][0][4096 + tid * 8]);  \
    glds16(Abase + (size_t)128 * KK + (KT) * 64, &AL[DD][1][tid * 8]);         \
    glds16(Abase + (size_t)192 * KK + (KT) * 64, &AL[DD][1][4096 + tid * 8]);  \
  } while (0)
#define STAGE_B(DD, KT)                                                        \
  do {                                                                         \
    glds16(Bbase + (size_t)0 * KK + (KT) * 64,   &BL[DD][0][tid * 8]);         \
    glds16(Bbase + (size_t)64 * KK + (KT) * 64,  &BL[DD][0][4096 + tid * 8]);  \
    glds16(Bbase + (size_t)128 * KK + (KT) * 64, &BL[DD][1][tid * 8]);         \
    glds16(Bbase + (size_t)192 * KK + (KT) * 64, &BL[DD][1][4096 + tid * 8]);  \
  } while (0)

  // issue A-frag reads for (MH,KH) of buf D into reg set S
#define RD_A(S, D, MH, KH)                                                     \
  do {                                                                         \
    _Pragma("unroll")                                                          \
    for (int q = 0; q < 4; ++q)                                                \
      aR[S][q] = *(const short8v*)&AL[D][wr][(((MH) * 4 + q) * 16 + l15) * 64  \
                                             + ((KH) ? ss1 : ss0)];            \
  } while (0)
#define RD_B(S, D, KH)                                                         \
  do {                                                                         \
    _Pragma("unroll")                                                          \
    for (int n = 0; n < 4; ++n)                                                \
      bR[S][n] = *(const short8v*)&BL[D][bhalf][(brow0 + n * 16) * 64          \
                                                + ((KH) ? ss1 : ss0)];         \
  } while (0)

#define MFMA1(a, b, c) c = __builtin_amdgcn_mfma_f32_16x16x32_bf16(a, b, c, 0, 0, 0)
#define CL16(AS, BS, MH)                                                       \
  do {                                                                         \
    __builtin_amdgcn_s_setprio(1);                                             \
    _Pragma("unroll")                                                          \
    for (int q = 0; q < 4; ++q) {                                              \
      MFMA1(aR[AS][q], bR[BS][0], acc[(MH) * 4 + q][0]);                       \
      MFMA1(aR[AS][q], bR[BS][1], acc[(MH) * 4 + q][1]);                       \
      MFMA1(aR[AS][q], bR[BS][2], acc[(MH) * 4 + q][2]);                       \
      MFMA1(aR[AS][q], bR[BS][3], acc[(MH) * 4 + q][3]);                       \
    }                                                                          \
    __builtin_amdgcn_s_setprio(0);                                             \
  } while (0)

#define BAR() __builtin_amdgcn_s_barrier()
#define VM0() asm volatile("s_waitcnt vmcnt(0)" ::: "memory")
#define VM4() asm volatile("s_waitcnt vmcnt(4)" ::: "memory")

  // ---- prologue: stage tile0 (A+B -> buf0), tile1's B -> buf1; first reads --
  STAGE_A(0, 0); STAGE_B(0, 0); STAGE_B(1, 1);
  VM4();             // tile0's 8 loads done (tile1's B stays outstanding)
  BAR();
  RD_A(0, 0, 0, 0);  // A(mh0,kh0) tile0 -> aR[0]
  RD_B(0, 0, 0);     // B(kh0)     tile0 -> bR[0]

  for (int u = 0; u < 16; ++u) {
    const int d = u & 1, dn = d ^ 1;

    // ph0: exec (mh0,kh0) on aR0/bR0; issue A(mh1,kh0)->aR1; stage_A(dn,u+1)
    if (u < 15) STAGE_A(dn, u + 1);
    RD_A(1, d, 1, 0);
    BAR();
    CL16(0, 0, 0);
    BAR();

    // ph1: exec (mh1,kh0) on aR1/bR0; issue A(mh0,kh1)->aR0, B(kh1)->bR1
    RD_A(0, d, 0, 1);
    RD_B(1, d, 1);
    BAR();
    CL16(1, 0, 1);
    BAR();

    // ph2: exec (mh0,kh1) on aR0/bR1; issue A(mh1,kh1)->aR1; vmcnt gate at end
    RD_A(1, d, 1, 1);
    BAR();
    CL16(0, 1, 0);
    VM0();             // tile u+1 (A@ph0, B@prev ph3) fully landed in buf dn
    BAR();

    // ph3: exec (mh1,kh1) on aR1/bR1; issue next-tile reads from dn; stage_B
    if (u < 15) { RD_A(0, dn, 0, 0); RD_B(0, dn, 0); }
    if (u < 14) STAGE_B(d, u + 2);
    BAR();
    CL16(1, 1, 1);
    BAR();
  }

#undef VM4
#undef VM0
#undef BAR
#undef CL16
#undef MFMA1
#undef RD_B
#undef RD_A
#undef STAGE_B
#undef STAGE_A

  // ---- epilogue: masked (strictly below anchor, off-diagonal) row/col max ----
  // C/D layout: col = lane&15, row = (lane>>4)*4 + reg
  const int rbase = bi * 256 + wr * 128;
  const int cbase = bj * 256 + wc * 64;

  float ar[32], ac[4];
#pragma unroll
  for (int m = 0; m < 8; ++m)
#pragma unroll
    for (int r = 0; r < 4; ++r)
      ar[m * 4 + r] = anchor[rbase + m * 16 + l4 * 4 + r];
#pragma unroll
  for (int n = 0; n < 4; ++n)
    ac[n] = anchor[cbase + n * 16 + l15];

  // row maxima: reduce over l15 (xor 1,2,4,8)
#pragma unroll
  for (int m = 0; m < 8; ++m) {
#pragma unroll
    for (int r = 0; r < 4; ++r) {
      const int rg = rbase + m * 16 + l4 * 4 + r;
      const float a = ar[m * 4 + r];
      uint32_t e = 0;
#pragma unroll
      for (int n = 0; n < 4; ++n) {
        const int cg = cbase + n * 16 + l15;
        float v = acc[m][n][r];
        if (v < a && rg != cg) { uint32_t fe = fenc(v); e = (fe > e) ? fe : e; }
      }
#pragma unroll
      for (int sh = 1; sh < 16; sh <<= 1) {
        uint32_t o = (uint32_t)__shfl_xor((int)e, sh, 64);
        e = (o > e) ? o : e;
      }
      if (l15 == 0 && e) atomicMax(&rowmax[rg], e);
    }
  }
  // col maxima: reduce over l4 (xor 16,32)
#pragma unroll
  for (int n = 0; n < 4; ++n) {
    const int cg = cbase + n * 16 + l15;
    const float a = ac[n];
    uint32_t e = 0;
#pragma unroll
    for (int m = 0; m < 8; ++m) {
#pragma unroll
      for (int r = 0; r < 4; ++r) {
        const int rg = rbase + m * 16 + l4 * 4 + r;
        float v = acc[m][n][r];
        if (v < a && rg != cg) { uint32_t fe = fenc(v); e = (fe > e) ? fe : e; }
      }
    }
    {
      uint32_t o = (uint32_t)__shfl_xor((int)e, 16, 64); e = (o > e) ? o : e;
      o = (uint32_t)__shfl_xor((int)e, 32, 64);          e = (o > e) ? o : e;
    }
    if (l4 == 0 && e) atomicMax(&colmax[cg], e);
  }
}

// ---------------- Kernel 4: hinge terms + mean -------------------------------
__global__ __launch_bounds__(256) void k_final(
    const float* __restrict__ anchor,
    const float* __restrict__ irr, const float* __restrict__ irf,
    const float* __restrict__ icr, const float* __restrict__ icf,
    const uint32_t* __restrict__ rowmax, const uint32_t* __restrict__ colmax,
    float* __restrict__ out) {
  float s = 0.f;
  for (int k = (int)threadIdx.x; k < NN; k += 256) {
    float a = anchor[k];
    float d1 = fmaxf(irr[k] - a + 1.0f, 0.f);
    uint32_t rm = rowmax[k];
    float imp2r = rm ? fdec(rm) : irf[k];
    float d2 = fmaxf(imp2r - a + 1.0f, 0.f);
    float e1 = fmaxf(icr[k] - a + 1.0f, 0.f);
    uint32_t cm = colmax[k];
    float imp2c = cm ? fdec(cm) : icf[k];
    float e2 = fmaxf(imp2c - a + 1.0f, 0.f);
    s += d1 + d2 + e1 + e2;
  }
  __shared__ float red[4];
  for (int m = 32; m >= 1; m >>= 1) s += __shfl_xor(s, m);
  if ((threadIdx.x & 63) == 0) red[threadIdx.x >> 6] = s;
  __syncthreads();
  if (threadIdx.x == 0) out[0] = (red[0] + red[1] + red[2] + red[3]) * (1.0f / NN);
}

// -----------------------------------------------------------------------------
extern "C" void kernel_launch(void* const* d_in, const int* in_sizes, int n_in,
                              void* d_out, int out_size, void* d_ws, size_t ws_size,
                              hipStream_t stream) {
  const float* X = (const float*)d_in[0];
  const float* Y = (const float*)d_in[1];
  float* out = (float*)d_out;

  char* ws = (char*)d_ws;
  float* anchor    = (float*)(ws + 0 * 16384);
  float* irr       = (float*)(ws + 1 * 16384);
  float* irf       = (float*)(ws + 2 * 16384);
  float* icr       = (float*)(ws + 3 * 16384);
  float* icf       = (float*)(ws + 4 * 16384);
  uint32_t* rowmax = (uint32_t*)(ws + 5 * 16384);
  uint32_t* colmax = (uint32_t*)(ws + 6 * 16384);
  ushort_t* Xb     = (ushort_t*)(ws + 256 * 1024);
  ushort_t* Yb     = Xb + (size_t)NN * KK;

  // subkeys = split(key(42), 4), partitionable: sk_i = threefry((0,42),(0,i))
  uint32_t sk[4][2];
  for (int i = 0; i < 4; ++i) tf2x32(0u, 42u, 0u, (uint32_t)i, &sk[i][0], &sk[i][1]);

  k_prep<<<4096, 256, 0, stream>>>((const float4*)X, (const float4*)Y,
                                   (ushort4*)Xb, (ushort4*)Yb, rowmax, colmax);

  k_dots<<<NN / 4, 256, 0, stream>>>(Xb, Yb,
      sk[0][0], sk[0][1], sk[1][0], sk[1][1], sk[2][0], sk[2][1], sk[3][0], sk[3][1],
      anchor, irr, irf, icr, icf);

  k_gemm_xp<<<256, 512, 0, stream>>>(Xb, Yb, anchor, rowmax, colmax);

  k_final<<<1, 256, 0, stream>>>(anchor, irr, irf, icr, icf, rowmax, colmax, out);
}